// Round 17
// baseline (261.845 us; speedup 1.0000x reference)
//
#include <hip/hip_runtime.h>

#define SQ 2048
#define DD 128
#define BHN 32                          // B*H = 2*16
// exp(s/sqrt(128)) == exp2(s * SC2); SC2 folded into Q fragments.
#define SC2 0.12751741934f

typedef __attribute__((ext_vector_type(8))) short bf16x8;
typedef __attribute__((ext_vector_type(4))) float f32x4;

// packed f32x2 -> bf16x2 (RNE), single HW instruction (no builtin on gfx950)
__device__ __forceinline__ unsigned cvtpk(float a, float b){
  unsigned r;
  asm("v_cvt_pk_bf16_f32 %0, %1, %2" : "=v"(r) : "v"(a), "v"(b));
  return r;
}
union U8 { unsigned u[4]; bf16x8 h; };

// async 16B global->LDS (dest = wave-uniform base + lane*16, linear)
__device__ __forceinline__ void gl_lds16(const void* g, void* l){
  __builtin_amdgcn_global_load_lds(
      (const __attribute__((address_space(1))) unsigned int*)g,
      (__attribute__((address_space(3))) unsigned int*)l, 16, 0, 0);
}

// ---------------------------------------------------------------------------
// Kernel 1 (verified R1-R16): quant-dequant K (per-token) and V (grouped-64).
// dqK:  [bh][s][d] rows of 256B, bytes within row XOR-swizzled by (s&7)<<4.
// dqVt: [bh][d][s] rows of 4096B; within each aligned 128B block (64 tokens)
//       bytes XOR-swizzled by (d&7)<<4.
// ---------------------------------------------------------------------------
__global__ __launch_bounds__(256) void qd_kernel(const float* __restrict__ K,
                                                 const float* __restrict__ V,
                                                 char* __restrict__ dqK,
                                                 char* __restrict__ dqVt){
  __shared__ float Vlds[128*65];
  const int t = threadIdx.x;
  const int bh = blockIdx.x >> 5;
  const int stile = blockIdx.x & 31;
  const int tt = t >> 2;
  const int q4 = t & 3;
  const int s = stile*64 + tt;
  const long ebase = ((long)(bh*SQ + s))*DD + 32*q4;

  float vals[32];
  {
    const float4* kp = (const float4*)(K + ebase);
    float am = 0.f;
    #pragma unroll
    for (int j=0;j<8;j++){
      float4 v4 = kp[j];
      vals[4*j+0]=v4.x; vals[4*j+1]=v4.y; vals[4*j+2]=v4.z; vals[4*j+3]=v4.w;
      am = fmaxf(am, fmaxf(fmaxf(fabsf(v4.x),fabsf(v4.y)),fmaxf(fabsf(v4.z),fabsf(v4.w))));
    }
    am = fmaxf(am, __shfl_xor(am,1));
    am = fmaxf(am, __shfl_xor(am,2));
    const float sc = fmaxf(am/7.0f, 1e-8f);
    #pragma unroll
    for (int j=0;j<32;j++){
      float qv = rintf(vals[j]/sc);
      qv = fminf(7.f, fmaxf(-7.f, qv));
      vals[j] = qv*sc;
    }
    const long rowb = ((long)(bh*SQ + s))*256;
    const int swz = (s & 7) << 4;
    #pragma unroll
    for (int c=0;c<4;c++){
      uint4 w;
      w.x = cvtpk(vals[8*c+0], vals[8*c+1]);
      w.y = cvtpk(vals[8*c+2], vals[8*c+3]);
      w.z = cvtpk(vals[8*c+4], vals[8*c+5]);
      w.w = cvtpk(vals[8*c+6], vals[8*c+7]);
      *(uint4*)(dqK + rowb + ((64*q4 + 16*c) ^ swz)) = w;
    }
  }
  {
    const float4* vp = (const float4*)(V + ebase);
    float am = 0.f;
    #pragma unroll
    for (int j=0;j<8;j++){
      float4 v4 = vp[j];
      vals[4*j+0]=v4.x; vals[4*j+1]=v4.y; vals[4*j+2]=v4.z; vals[4*j+3]=v4.w;
      am = fmaxf(am, fmaxf(fmaxf(fabsf(v4.x),fabsf(v4.y)),fmaxf(fabsf(v4.z),fabsf(v4.w))));
    }
    am = fmaxf(am, __shfl_xor(am,1));
    const float sc = fmaxf(am/7.0f, 1e-8f);
    #pragma unroll
    for (int j=0;j<32;j++){
      float qv = rintf(vals[j]/sc);
      qv = fminf(7.f, fmaxf(-7.f, qv));
      Vlds[(32*q4 + j)*65 + tt] = qv*sc;
    }
  }
  __syncthreads();
  #pragma unroll
  for (int m=0;m<4;m++){
    const int chunk = m*256 + t;
    const int d = chunk >> 3;
    const int c = chunk & 7;
    uint4 w;
    const float* f = &Vlds[d*65 + 8*c];
    w.x = cvtpk(f[0], f[1]);
    w.y = cvtpk(f[2], f[3]);
    w.z = cvtpk(f[4], f[5]);
    w.w = cvtpk(f[6], f[7]);
    const long ob = ((long)(bh*DD + d))*4096 + (long)stile*128 + ((16*c) ^ ((d&7)<<4));
    *(uint4*)(dqVt + ob) = w;
  }
}

// ---------------------------------------------------------------------------
// Fused attention (R15 structure, best @226.3us; zero-fill hoisted).
// 512 blocks (2/CU), 4 waves, 80KB LDS; strips qtA=31-p and qtB=p; every
// wave owns 16 rows of each strip. SC2 pre-folded into Q fragments.
// PASS 1: K+V LDS-staged double-buffer; swapped QK^T; wave-private Et; PV.
// ZERO-FILL of the masked W region moved BEFORE pass 2 (dependency-free,
// barrier-free region): deep store backlog drains during pass-2's MFMA/exp
// gaps -> write pipe busy across the whole pass-2 window.
// PASS 2: barrier-free; K global->reg (L2-hot); normal f32x4 W stores.
// ---------------------------------------------------------------------------
__global__ __launch_bounds__(256,2) void attn_fused(const float* __restrict__ Q,
    const char* __restrict__ dqK, const char* __restrict__ dqVt,
    float* __restrict__ Out, float* __restrict__ Wout){
  __shared__ __attribute__((aligned(16))) char Kt[2][16384];
  __shared__ __attribute__((aligned(16))) char Vt[2][16384];
  __shared__ __attribute__((aligned(16))) char Et[4][4096];

  const int bid = blockIdx.x;              // 512 blocks
  const int xcd = bid & 7;                 // chunk bh per XCD for L2 locality
  const int loc = bid >> 3;                // 0..63
  const int bh  = xcd*4 + (loc & 3);
  const int i   = loc >> 2;                // 0..15
  const int p   = (i < 8) ? i : (23 - i);  // co-resident pairs (i,15-i)
  const int t = threadIdx.x;
  const int lane = t & 63;
  const int w = t >> 6;                    // 0..3
  const int l15 = lane & 15, l4 = lane >> 4;
  const int swz = (l15 & 7) << 4;

  const int qtA = 31 - p, qtB = p;
  const int q0A = qtA*64, q0B = qtB*64;
  const int nktA = qtA + 1;                // block loop length
  const int nktB = qtB + 1;
  const int rA = q0A + 16*w + l15;         // wave's strip-A row (this lane)
  const int rB = q0B + 16*w + l15;         // wave's strip-B row

  // Q B-fragments pre-scaled by SC2: g=0 -> strip A rows, g=1 -> strip B
  bf16x8 qa[2][4];
  #pragma unroll
  for (int g=0; g<2; ++g){
    const int qrow = g ? rB : rA;
    const float* qb = Q + ((long)(bh*SQ) + qrow)*DD + 8*l4;
    #pragma unroll
    for (int kk=0;kk<4;kk++){
      float4 a = *(const float4*)(qb + 32*kk);
      float4 b = *(const float4*)(qb + 32*kk + 4);
      U8 cv;
      cv.u[0] = cvtpk(a.x*SC2, a.y*SC2);
      cv.u[1] = cvtpk(a.z*SC2, a.w*SC2);
      cv.u[2] = cvtpk(b.x*SC2, b.y*SC2);
      cv.u[3] = cvtpk(b.z*SC2, b.w*SC2);
      qa[g][kk] = cv.h;
    }
  }

  const char* Kb = dqK + (long)bh*SQ*256;
  const char* Vb = dqVt + (long)bh*DD*4096;

  const f32x4 z4 = {0.f,0.f,0.f,0.f};
  f32x4 oacc[2][8] = {{z4,z4,z4,z4,z4,z4,z4,z4},{z4,z4,z4,z4,z4,z4,z4,z4}};
  float ssum[2] = {0.f, 0.f};
  char* eb = &Et[w][0];

  auto stageKV = [&](int buf, int kt){
    const char* ks = Kb + (long)kt*16384;
    #pragma unroll
    for (int it=0;it<4;it++)
      gl_lds16(ks + it*4096 + t*16, &Kt[buf][it*4096 + t*16]);
    const char* vs = Vb + (long)kt*128;
    #pragma unroll
    for (int it=0;it<4;it++)
      gl_lds16(vs + (long)(it*32 + (t>>3))*4096 + (t&7)*16, &Vt[buf][it*4096 + t*16]);
  };

  // ======================= PASS 1 =======================
  stageKV(0, 0);
  __syncthreads();
  int cur = 0;
  for (int kt=0; kt<nktA; ++kt){
    if (kt+1 < nktA) stageKV(cur^1, kt+1);
    const bool doB = (kt < nktB);
    const int k0 = kt*64;

    // --- QK^T swapped; K-frags read once, feed 1 or 2 strip groups ---
    f32x4 sacc[2][4] = {{z4,z4,z4,z4},{z4,z4,z4,z4}};
    {
      const char* kbase = &Kt[cur][0] + l15*256;
      __builtin_amdgcn_s_setprio(1);
      if (doB){
        #pragma unroll
        for (int cf=0;cf<4;cf++){
          #pragma unroll
          for (int kk=0;kk<4;kk++){
            bf16x8 kb = *(const bf16x8*)(kbase + cf*4096 + ((64*kk+16*l4) ^ swz));
            sacc[0][cf] = __builtin_amdgcn_mfma_f32_16x16x32_bf16(kb, qa[0][kk], sacc[0][cf], 0,0,0);
            sacc[1][cf] = __builtin_amdgcn_mfma_f32_16x16x32_bf16(kb, qa[1][kk], sacc[1][cf], 0,0,0);
          }
        }
      } else {
        #pragma unroll
        for (int cf=0;cf<4;cf++){
          #pragma unroll
          for (int kk=0;kk<4;kk++){
            bf16x8 kb = *(const bf16x8*)(kbase + cf*4096 + ((64*kk+16*l4) ^ swz));
            sacc[0][cf] = __builtin_amdgcn_mfma_f32_16x16x32_bf16(kb, qa[0][kk], sacc[0][cf], 0,0,0);
          }
        }
      }
      __builtin_amdgcn_s_setprio(0);
    }

    // --- exp (+mask on each strip's diagonal tile) -> Et ---
    {  // strip A (rows 0..15 of wave's Et)
      if (kt < qtA){
        #pragma unroll
        for (int cf=0;cf<4;cf++){
          float e0 = exp2f(sacc[0][cf][0]);
          float e1 = exp2f(sacc[0][cf][1]);
          float e2 = exp2f(sacc[0][cf][2]);
          float e3 = exp2f(sacc[0][cf][3]);
          ssum[0] += (e0+e1) + (e2+e3);
          uint2 wp; wp.x = cvtpk(e0,e1); wp.y = cvtpk(e2,e3);
          *(uint2*)(eb + l15*128 + ((32*cf + 8*l4) ^ swz)) = wp;
        }
      } else {
        #pragma unroll
        for (int cf=0;cf<4;cf++){
          const int tok0 = k0 + 16*cf + 4*l4;
          float e0 = (tok0+0 <= rA) ? exp2f(sacc[0][cf][0]) : 0.f;
          float e1 = (tok0+1 <= rA) ? exp2f(sacc[0][cf][1]) : 0.f;
          float e2 = (tok0+2 <= rA) ? exp2f(sacc[0][cf][2]) : 0.f;
          float e3 = (tok0+3 <= rA) ? exp2f(sacc[0][cf][3]) : 0.f;
          ssum[0] += (e0+e1) + (e2+e3);
          uint2 wp; wp.x = cvtpk(e0,e1); wp.y = cvtpk(e2,e3);
          *(uint2*)(eb + l15*128 + ((32*cf + 8*l4) ^ swz)) = wp;
        }
      }
    }
    if (doB){  // strip B (rows 16..31 of wave's Et)
      const int lr = 16 + l15;
      if (kt < qtB){
        #pragma unroll
        for (int cf=0;cf<4;cf++){
          float e0 = exp2f(sacc[1][cf][0]);
          float e1 = exp2f(sacc[1][cf][1]);
          float e2 = exp2f(sacc[1][cf][2]);
          float e3 = exp2f(sacc[1][cf][3]);
          ssum[1] += (e0+e1) + (e2+e3);
          uint2 wp; wp.x = cvtpk(e0,e1); wp.y = cvtpk(e2,e3);
          *(uint2*)(eb + lr*128 + ((32*cf + 8*l4) ^ swz)) = wp;
        }
      } else {
        #pragma unroll
        for (int cf=0;cf<4;cf++){
          const int tok0 = k0 + 16*cf + 4*l4;
          float e0 = (tok0+0 <= rB) ? exp2f(sacc[1][cf][0]) : 0.f;
          float e1 = (tok0+1 <= rB) ? exp2f(sacc[1][cf][1]) : 0.f;
          float e2 = (tok0+2 <= rB) ? exp2f(sacc[1][cf][2]) : 0.f;
          float e3 = (tok0+3 <= rB) ? exp2f(sacc[1][cf][3]) : 0.f;
          ssum[1] += (e0+e1) + (e2+e3);
          uint2 wp; wp.x = cvtpk(e0,e1); wp.y = cvtpk(e2,e3);
          *(uint2*)(eb + lr*128 + ((32*cf + 8*l4) ^ swz)) = wp;
        }
      }
    }

    // --- PV; V-frags read once from LDS, feed 1 or 2 groups ---
    {
      const char* vbase = &Vt[cur][0] + l15*128;
      __builtin_amdgcn_s_setprio(1);
      if (doB){
        #pragma unroll
        for (int kc=0;kc<2;kc++){
          const int eo = (64*kc + 16*l4) ^ swz;
          bf16x8 ea0 = *(const bf16x8*)(eb + l15*128 + eo);
          bf16x8 ea1 = *(const bf16x8*)(eb + (16+l15)*128 + eo);
          #pragma unroll
          for (int df=0;df<8;df++){
            bf16x8 vv = *(const bf16x8*)(vbase + df*2048 + eo);
            oacc[0][df] = __builtin_amdgcn_mfma_f32_16x16x32_bf16(ea0, vv, oacc[0][df], 0,0,0);
            oacc[1][df] = __builtin_amdgcn_mfma_f32_16x16x32_bf16(ea1, vv, oacc[1][df], 0,0,0);
          }
        }
      } else {
        #pragma unroll
        for (int kc=0;kc<2;kc++){
          const int eo = (64*kc + 16*l4) ^ swz;
          bf16x8 ea0 = *(const bf16x8*)(eb + l15*128 + eo);
          #pragma unroll
          for (int df=0;df<8;df++){
            bf16x8 vv = *(const bf16x8*)(vbase + df*2048 + eo);
            oacc[0][df] = __builtin_amdgcn_mfma_f32_16x16x32_bf16(ea0, vv, oacc[0][df], 0,0,0);
          }
        }
      }
      __builtin_amdgcn_s_setprio(0);
    }
    __syncthreads();   // buffer rotation + stage drain
    cur ^= 1;
  }

  // row sums + O write; si kept in registers for pass 2
  float si[2];
  #pragma unroll
  for (int g=0; g<2; ++g){
    float sm = ssum[g];
    sm += __shfl_xor(sm, 16);
    sm += __shfl_xor(sm, 32);
    si[g] = 1.0f / sm;          // uniform across l4 for each l15
    float invr[4];
    #pragma unroll
    for (int ii=0;ii<4;ii++) invr[ii] = __shfl(si[g], 4*l4+ii);
    const int rb0 = (g ? q0B : q0A) + 16*w;
    float* ob = Out + ((long)(bh*SQ) + rb0)*DD;
    #pragma unroll
    for (int df=0;df<8;df++){
      #pragma unroll
      for (int ii=0;ii<4;ii++)
        ob[(4*l4+ii)*DD + 16*df + l15] = oacc[g][df][ii]*invr[ii];
    }
  }

  float* Wbase = Wout + (long)bh*SQ*SQ;

  // ---- zero-fill masked W region FIRST (dependency-free, barrier-free):
  // builds a deep store backlog that drains during pass-2's compute gaps.
  const f32x4 zz = {0.f,0.f,0.f,0.f};
  {
    const int z0 = nktA*64;
    for (int rr=0; rr<16 && z0 < SQ; rr++){
      float* row = Wbase + (long)(q0A + 16*w + rr)*SQ;
      for (int c = z0 + 4*lane; c < SQ; c += 256)
        *(f32x4*)(row + c) = zz;
    }
  }
  {
    const int z0 = nktB*64;
    for (int rr=0; rr<16; rr++){
      float* row = Wbase + (long)(q0B + 16*w + rr)*SQ;
      for (int c = z0 + 4*lane; c < SQ; c += 256)
        *(f32x4*)(row + c) = zz;
    }
  }

  // ======================= PASS 2 (barrier-free) =======================
  // Per wave: K tiles global->reg (L2-hot), recompute QK^T for its A-rows
  // (and B-rows while kt<nktB), normal f32x4 W stores. No barriers.
  float* wrowA = Wbase + (long)rA*SQ;
  float* wrowB = Wbase + (long)rB*SQ;

  for (int kt=0; kt<nktA; ++kt){
    const int k0 = kt*64;
    const char* kr = Kb + (long)kt*16384 + l15*256;
    const bool doB = (kt < nktB);

    bf16x8 kb[4][4];
    #pragma unroll
    for (int cf=0;cf<4;cf++){
      #pragma unroll
      for (int kk=0;kk<4;kk++)
        kb[cf][kk] = *(const bf16x8*)(kr + cf*4096 + ((64*kk+16*l4) ^ swz));
    }

    f32x4 sacc[2][4] = {{z4,z4,z4,z4},{z4,z4,z4,z4}};
    __builtin_amdgcn_s_setprio(1);
    if (doB){
      #pragma unroll
      for (int cf=0;cf<4;cf++){
        #pragma unroll
        for (int kk=0;kk<4;kk++){
          sacc[0][cf] = __builtin_amdgcn_mfma_f32_16x16x32_bf16(kb[cf][kk], qa[0][kk], sacc[0][cf], 0,0,0);
          sacc[1][cf] = __builtin_amdgcn_mfma_f32_16x16x32_bf16(kb[cf][kk], qa[1][kk], sacc[1][cf], 0,0,0);
        }
      }
    } else {
      #pragma unroll
      for (int cf=0;cf<4;cf++){
        #pragma unroll
        for (int kk=0;kk<4;kk++)
          sacc[0][cf] = __builtin_amdgcn_mfma_f32_16x16x32_bf16(kb[cf][kk], qa[0][kk], sacc[0][cf], 0,0,0);
      }
    }
    __builtin_amdgcn_s_setprio(0);

    // strip A stores
    if (kt < qtA){
      #pragma unroll
      for (int cf=0;cf<4;cf++){
        const int tok0 = k0 + 16*cf + 4*l4;
        f32x4 wv;
        wv[0] = exp2f(sacc[0][cf][0])*si[0];
        wv[1] = exp2f(sacc[0][cf][1])*si[0];
        wv[2] = exp2f(sacc[0][cf][2])*si[0];
        wv[3] = exp2f(sacc[0][cf][3])*si[0];
        *(f32x4*)(wrowA + tok0) = wv;
      }
    } else {
      #pragma unroll
      for (int cf=0;cf<4;cf++){
        const int tok0 = k0 + 16*cf + 4*l4;
        f32x4 wv;
        wv[0] = (tok0+0 <= rA) ? exp2f(sacc[0][cf][0])*si[0] : 0.f;
        wv[1] = (tok0+1 <= rA) ? exp2f(sacc[0][cf][1])*si[0] : 0.f;
        wv[2] = (tok0+2 <= rA) ? exp2f(sacc[0][cf][2])*si[0] : 0.f;
        wv[3] = (tok0+3 <= rA) ? exp2f(sacc[0][cf][3])*si[0] : 0.f;
        *(f32x4*)(wrowA + tok0) = wv;
      }
    }
    // strip B stores
    if (doB){
      if (kt < qtB){
        #pragma unroll
        for (int cf=0;cf<4;cf++){
          const int tok0 = k0 + 16*cf + 4*l4;
          f32x4 wv;
          wv[0] = exp2f(sacc[1][cf][0])*si[1];
          wv[1] = exp2f(sacc[1][cf][1])*si[1];
          wv[2] = exp2f(sacc[1][cf][2])*si[1];
          wv[3] = exp2f(sacc[1][cf][3])*si[1];
          *(f32x4*)(wrowB + tok0) = wv;
        }
      } else {
        #pragma unroll
        for (int cf=0;cf<4;cf++){
          const int tok0 = k0 + 16*cf + 4*l4;
          f32x4 wv;
          wv[0] = (tok0+0 <= rB) ? exp2f(sacc[1][cf][0])*si[1] : 0.f;
          wv[1] = (tok0+1 <= rB) ? exp2f(sacc[1][cf][1])*si[1] : 0.f;
          wv[2] = (tok0+2 <= rB) ? exp2f(sacc[1][cf][2])*si[1] : 0.f;
          wv[3] = (tok0+3 <= rB) ? exp2f(sacc[1][cf][3])*si[1] : 0.f;
          *(f32x4*)(wrowB + tok0) = wv;
        }
      }
    }
  }
}

extern "C" void kernel_launch(void* const* d_in, const int* in_sizes, int n_in,
                              void* d_out, int out_size, void* d_ws, size_t ws_size,
                              hipStream_t stream) {
  const float* Q = (const float*)d_in[0];
  const float* K = (const float*)d_in[1];
  const float* V = (const float*)d_in[2];
  float* Out = (float*)d_out;
  float* Wout = (float*)d_out + (size_t)BHN*SQ*DD;
  char* dqK  = (char*)d_ws;                                // 16 MB
  char* dqVt = (char*)d_ws + (size_t)BHN*SQ*DD*2;          // 16 MB

  qd_kernel<<<BHN*32, 256, 0, stream>>>(K, V, dqK, dqVt);
  attn_fused<<<512, 256, 0, stream>>>(Q, dqK, dqVt, Out, Wout);
}

// Round 18
// 226.297 us; speedup vs baseline: 1.1571x; 1.1571x over previous
//
#include <hip/hip_runtime.h>

#define SQ 2048
#define DD 128
#define BHN 32                          // B*H = 2*16
// exp(s/sqrt(128)) == exp2(s * SC2); SC2 folded into Q fragments.
#define SC2 0.12751741934f

typedef __attribute__((ext_vector_type(8))) short bf16x8;
typedef __attribute__((ext_vector_type(4))) float f32x4;

// packed f32x2 -> bf16x2 (RNE), single HW instruction (no builtin on gfx950)
__device__ __forceinline__ unsigned cvtpk(float a, float b){
  unsigned r;
  asm("v_cvt_pk_bf16_f32 %0, %1, %2" : "=v"(r) : "v"(a), "v"(b));
  return r;
}
union U8 { unsigned u[4]; bf16x8 h; };

// async 16B global->LDS (dest = wave-uniform base + lane*16, linear)
__device__ __forceinline__ void gl_lds16(const void* g, void* l){
  __builtin_amdgcn_global_load_lds(
      (const __attribute__((address_space(1))) unsigned int*)g,
      (__attribute__((address_space(3))) unsigned int*)l, 16, 0, 0);
}

// ---------------------------------------------------------------------------
// Kernel 1 (verified R1-R17): quant-dequant K (per-token) and V (grouped-64).
// dqK:  [bh][s][d] rows of 256B, bytes within row XOR-swizzled by (s&7)<<4.
// dqVt: [bh][d][s] rows of 4096B; within each aligned 128B block (64 tokens)
//       bytes XOR-swizzled by (d&7)<<4.
// ---------------------------------------------------------------------------
__global__ __launch_bounds__(256) void qd_kernel(const float* __restrict__ K,
                                                 const float* __restrict__ V,
                                                 char* __restrict__ dqK,
                                                 char* __restrict__ dqVt){
  __shared__ float Vlds[128*65];
  const int t = threadIdx.x;
  const int bh = blockIdx.x >> 5;
  const int stile = blockIdx.x & 31;
  const int tt = t >> 2;
  const int q4 = t & 3;
  const int s = stile*64 + tt;
  const long ebase = ((long)(bh*SQ + s))*DD + 32*q4;

  float vals[32];
  {
    const float4* kp = (const float4*)(K + ebase);
    float am = 0.f;
    #pragma unroll
    for (int j=0;j<8;j++){
      float4 v4 = kp[j];
      vals[4*j+0]=v4.x; vals[4*j+1]=v4.y; vals[4*j+2]=v4.z; vals[4*j+3]=v4.w;
      am = fmaxf(am, fmaxf(fmaxf(fabsf(v4.x),fabsf(v4.y)),fmaxf(fabsf(v4.z),fabsf(v4.w))));
    }
    am = fmaxf(am, __shfl_xor(am,1));
    am = fmaxf(am, __shfl_xor(am,2));
    const float sc = fmaxf(am/7.0f, 1e-8f);
    #pragma unroll
    for (int j=0;j<32;j++){
      float qv = rintf(vals[j]/sc);
      qv = fminf(7.f, fmaxf(-7.f, qv));
      vals[j] = qv*sc;
    }
    const long rowb = ((long)(bh*SQ + s))*256;
    const int swz = (s & 7) << 4;
    #pragma unroll
    for (int c=0;c<4;c++){
      uint4 w;
      w.x = cvtpk(vals[8*c+0], vals[8*c+1]);
      w.y = cvtpk(vals[8*c+2], vals[8*c+3]);
      w.z = cvtpk(vals[8*c+4], vals[8*c+5]);
      w.w = cvtpk(vals[8*c+6], vals[8*c+7]);
      *(uint4*)(dqK + rowb + ((64*q4 + 16*c) ^ swz)) = w;
    }
  }
  {
    const float4* vp = (const float4*)(V + ebase);
    float am = 0.f;
    #pragma unroll
    for (int j=0;j<8;j++){
      float4 v4 = vp[j];
      vals[4*j+0]=v4.x; vals[4*j+1]=v4.y; vals[4*j+2]=v4.z; vals[4*j+3]=v4.w;
      am = fmaxf(am, fmaxf(fmaxf(fabsf(v4.x),fabsf(v4.y)),fmaxf(fabsf(v4.z),fabsf(v4.w))));
    }
    am = fmaxf(am, __shfl_xor(am,1));
    const float sc = fmaxf(am/7.0f, 1e-8f);
    #pragma unroll
    for (int j=0;j<32;j++){
      float qv = rintf(vals[j]/sc);
      qv = fminf(7.f, fmaxf(-7.f, qv));
      Vlds[(32*q4 + j)*65 + tt] = qv*sc;
    }
  }
  __syncthreads();
  #pragma unroll
  for (int m=0;m<4;m++){
    const int chunk = m*256 + t;
    const int d = chunk >> 3;
    const int c = chunk & 7;
    uint4 w;
    const float* f = &Vlds[d*65 + 8*c];
    w.x = cvtpk(f[0], f[1]);
    w.y = cvtpk(f[2], f[3]);
    w.z = cvtpk(f[4], f[5]);
    w.w = cvtpk(f[6], f[7]);
    const long ob = ((long)(bh*DD + d))*4096 + (long)stile*128 + ((16*c) ^ ((d&7)<<4));
    *(uint4*)(dqVt + ob) = w;
  }
}

// ---------------------------------------------------------------------------
// Fused attention (R15, validated best @226.3us).
// 512 blocks (2/CU), 4 waves, 80KB LDS; strips qtA=31-p and qtB=p; every
// wave owns 16 rows of each strip. SC2 pre-folded into Q fragments.
// PASS 1: K+V LDS-staged double-buffer; swapped QK^T; wave-private Et; PV.
// PASS 2: barrier-free; K global->reg (L2-hot); normal f32x4 W stores;
// zero-fill of the masked region trails (R17 showed hoisting it regresses).
// ---------------------------------------------------------------------------
__global__ __launch_bounds__(256,2) void attn_fused(const float* __restrict__ Q,
    const char* __restrict__ dqK, const char* __restrict__ dqVt,
    float* __restrict__ Out, float* __restrict__ Wout){
  __shared__ __attribute__((aligned(16))) char Kt[2][16384];
  __shared__ __attribute__((aligned(16))) char Vt[2][16384];
  __shared__ __attribute__((aligned(16))) char Et[4][4096];

  const int bid = blockIdx.x;              // 512 blocks
  const int xcd = bid & 7;                 // chunk bh per XCD for L2 locality
  const int loc = bid >> 3;                // 0..63
  const int bh  = xcd*4 + (loc & 3);
  const int i   = loc >> 2;                // 0..15
  const int p   = (i < 8) ? i : (23 - i);  // co-resident pairs (i,15-i)
  const int t = threadIdx.x;
  const int lane = t & 63;
  const int w = t >> 6;                    // 0..3
  const int l15 = lane & 15, l4 = lane >> 4;
  const int swz = (l15 & 7) << 4;

  const int qtA = 31 - p, qtB = p;
  const int q0A = qtA*64, q0B = qtB*64;
  const int nktA = qtA + 1;                // block loop length
  const int nktB = qtB + 1;
  const int rA = q0A + 16*w + l15;         // wave's strip-A row (this lane)
  const int rB = q0B + 16*w + l15;         // wave's strip-B row

  // Q B-fragments pre-scaled by SC2: g=0 -> strip A rows, g=1 -> strip B
  bf16x8 qa[2][4];
  #pragma unroll
  for (int g=0; g<2; ++g){
    const int qrow = g ? rB : rA;
    const float* qb = Q + ((long)(bh*SQ) + qrow)*DD + 8*l4;
    #pragma unroll
    for (int kk=0;kk<4;kk++){
      float4 a = *(const float4*)(qb + 32*kk);
      float4 b = *(const float4*)(qb + 32*kk + 4);
      U8 cv;
      cv.u[0] = cvtpk(a.x*SC2, a.y*SC2);
      cv.u[1] = cvtpk(a.z*SC2, a.w*SC2);
      cv.u[2] = cvtpk(b.x*SC2, b.y*SC2);
      cv.u[3] = cvtpk(b.z*SC2, b.w*SC2);
      qa[g][kk] = cv.h;
    }
  }

  const char* Kb = dqK + (long)bh*SQ*256;
  const char* Vb = dqVt + (long)bh*DD*4096;

  const f32x4 z4 = {0.f,0.f,0.f,0.f};
  f32x4 oacc[2][8] = {{z4,z4,z4,z4,z4,z4,z4,z4},{z4,z4,z4,z4,z4,z4,z4,z4}};
  float ssum[2] = {0.f, 0.f};
  char* eb = &Et[w][0];

  auto stageKV = [&](int buf, int kt){
    const char* ks = Kb + (long)kt*16384;
    #pragma unroll
    for (int it=0;it<4;it++)
      gl_lds16(ks + it*4096 + t*16, &Kt[buf][it*4096 + t*16]);
    const char* vs = Vb + (long)kt*128;
    #pragma unroll
    for (int it=0;it<4;it++)
      gl_lds16(vs + (long)(it*32 + (t>>3))*4096 + (t&7)*16, &Vt[buf][it*4096 + t*16]);
  };

  // ======================= PASS 1 =======================
  stageKV(0, 0);
  __syncthreads();
  int cur = 0;
  for (int kt=0; kt<nktA; ++kt){
    if (kt+1 < nktA) stageKV(cur^1, kt+1);
    const bool doB = (kt < nktB);
    const int k0 = kt*64;

    // --- QK^T swapped; K-frags read once, feed 1 or 2 strip groups ---
    f32x4 sacc[2][4] = {{z4,z4,z4,z4},{z4,z4,z4,z4}};
    {
      const char* kbase = &Kt[cur][0] + l15*256;
      __builtin_amdgcn_s_setprio(1);
      if (doB){
        #pragma unroll
        for (int cf=0;cf<4;cf++){
          #pragma unroll
          for (int kk=0;kk<4;kk++){
            bf16x8 kb = *(const bf16x8*)(kbase + cf*4096 + ((64*kk+16*l4) ^ swz));
            sacc[0][cf] = __builtin_amdgcn_mfma_f32_16x16x32_bf16(kb, qa[0][kk], sacc[0][cf], 0,0,0);
            sacc[1][cf] = __builtin_amdgcn_mfma_f32_16x16x32_bf16(kb, qa[1][kk], sacc[1][cf], 0,0,0);
          }
        }
      } else {
        #pragma unroll
        for (int cf=0;cf<4;cf++){
          #pragma unroll
          for (int kk=0;kk<4;kk++){
            bf16x8 kb = *(const bf16x8*)(kbase + cf*4096 + ((64*kk+16*l4) ^ swz));
            sacc[0][cf] = __builtin_amdgcn_mfma_f32_16x16x32_bf16(kb, qa[0][kk], sacc[0][cf], 0,0,0);
          }
        }
      }
      __builtin_amdgcn_s_setprio(0);
    }

    // --- exp (+mask on each strip's diagonal tile) -> Et ---
    {  // strip A (rows 0..15 of wave's Et)
      if (kt < qtA){
        #pragma unroll
        for (int cf=0;cf<4;cf++){
          float e0 = exp2f(sacc[0][cf][0]);
          float e1 = exp2f(sacc[0][cf][1]);
          float e2 = exp2f(sacc[0][cf][2]);
          float e3 = exp2f(sacc[0][cf][3]);
          ssum[0] += (e0+e1) + (e2+e3);
          uint2 wp; wp.x = cvtpk(e0,e1); wp.y = cvtpk(e2,e3);
          *(uint2*)(eb + l15*128 + ((32*cf + 8*l4) ^ swz)) = wp;
        }
      } else {
        #pragma unroll
        for (int cf=0;cf<4;cf++){
          const int tok0 = k0 + 16*cf + 4*l4;
          float e0 = (tok0+0 <= rA) ? exp2f(sacc[0][cf][0]) : 0.f;
          float e1 = (tok0+1 <= rA) ? exp2f(sacc[0][cf][1]) : 0.f;
          float e2 = (tok0+2 <= rA) ? exp2f(sacc[0][cf][2]) : 0.f;
          float e3 = (tok0+3 <= rA) ? exp2f(sacc[0][cf][3]) : 0.f;
          ssum[0] += (e0+e1) + (e2+e3);
          uint2 wp; wp.x = cvtpk(e0,e1); wp.y = cvtpk(e2,e3);
          *(uint2*)(eb + l15*128 + ((32*cf + 8*l4) ^ swz)) = wp;
        }
      }
    }
    if (doB){  // strip B (rows 16..31 of wave's Et)
      const int lr = 16 + l15;
      if (kt < qtB){
        #pragma unroll
        for (int cf=0;cf<4;cf++){
          float e0 = exp2f(sacc[1][cf][0]);
          float e1 = exp2f(sacc[1][cf][1]);
          float e2 = exp2f(sacc[1][cf][2]);
          float e3 = exp2f(sacc[1][cf][3]);
          ssum[1] += (e0+e1) + (e2+e3);
          uint2 wp; wp.x = cvtpk(e0,e1); wp.y = cvtpk(e2,e3);
          *(uint2*)(eb + lr*128 + ((32*cf + 8*l4) ^ swz)) = wp;
        }
      } else {
        #pragma unroll
        for (int cf=0;cf<4;cf++){
          const int tok0 = k0 + 16*cf + 4*l4;
          float e0 = (tok0+0 <= rB) ? exp2f(sacc[1][cf][0]) : 0.f;
          float e1 = (tok0+1 <= rB) ? exp2f(sacc[1][cf][1]) : 0.f;
          float e2 = (tok0+2 <= rB) ? exp2f(sacc[1][cf][2]) : 0.f;
          float e3 = (tok0+3 <= rB) ? exp2f(sacc[1][cf][3]) : 0.f;
          ssum[1] += (e0+e1) + (e2+e3);
          uint2 wp; wp.x = cvtpk(e0,e1); wp.y = cvtpk(e2,e3);
          *(uint2*)(eb + lr*128 + ((32*cf + 8*l4) ^ swz)) = wp;
        }
      }
    }

    // --- PV; V-frags read once from LDS, feed 1 or 2 groups ---
    {
      const char* vbase = &Vt[cur][0] + l15*128;
      __builtin_amdgcn_s_setprio(1);
      if (doB){
        #pragma unroll
        for (int kc=0;kc<2;kc++){
          const int eo = (64*kc + 16*l4) ^ swz;
          bf16x8 ea0 = *(const bf16x8*)(eb + l15*128 + eo);
          bf16x8 ea1 = *(const bf16x8*)(eb + (16+l15)*128 + eo);
          #pragma unroll
          for (int df=0;df<8;df++){
            bf16x8 vv = *(const bf16x8*)(vbase + df*2048 + eo);
            oacc[0][df] = __builtin_amdgcn_mfma_f32_16x16x32_bf16(ea0, vv, oacc[0][df], 0,0,0);
            oacc[1][df] = __builtin_amdgcn_mfma_f32_16x16x32_bf16(ea1, vv, oacc[1][df], 0,0,0);
          }
        }
      } else {
        #pragma unroll
        for (int kc=0;kc<2;kc++){
          const int eo = (64*kc + 16*l4) ^ swz;
          bf16x8 ea0 = *(const bf16x8*)(eb + l15*128 + eo);
          #pragma unroll
          for (int df=0;df<8;df++){
            bf16x8 vv = *(const bf16x8*)(vbase + df*2048 + eo);
            oacc[0][df] = __builtin_amdgcn_mfma_f32_16x16x32_bf16(ea0, vv, oacc[0][df], 0,0,0);
          }
        }
      }
      __builtin_amdgcn_s_setprio(0);
    }
    __syncthreads();   // buffer rotation + stage drain
    cur ^= 1;
  }

  // row sums + O write; si kept in registers for pass 2
  float si[2];
  #pragma unroll
  for (int g=0; g<2; ++g){
    float sm = ssum[g];
    sm += __shfl_xor(sm, 16);
    sm += __shfl_xor(sm, 32);
    si[g] = 1.0f / sm;          // uniform across l4 for each l15
    float invr[4];
    #pragma unroll
    for (int ii=0;ii<4;ii++) invr[ii] = __shfl(si[g], 4*l4+ii);
    const int rb0 = (g ? q0B : q0A) + 16*w;
    float* ob = Out + ((long)(bh*SQ) + rb0)*DD;
    #pragma unroll
    for (int df=0;df<8;df++){
      #pragma unroll
      for (int ii=0;ii<4;ii++)
        ob[(4*l4+ii)*DD + 16*df + l15] = oacc[g][df][ii]*invr[ii];
    }
  }

  // ======================= PASS 2 (barrier-free) =======================
  // Per wave: K tiles global->reg (L2-hot), recompute QK^T for its A-rows
  // (and B-rows while kt<nktB), normal f32x4 W stores. No barriers.
  float* Wbase = Wout + (long)bh*SQ*SQ;
  float* wrowA = Wbase + (long)rA*SQ;
  float* wrowB = Wbase + (long)rB*SQ;

  for (int kt=0; kt<nktA; ++kt){
    const int k0 = kt*64;
    const char* kr = Kb + (long)kt*16384 + l15*256;
    const bool doB = (kt < nktB);

    bf16x8 kb[4][4];
    #pragma unroll
    for (int cf=0;cf<4;cf++){
      #pragma unroll
      for (int kk=0;kk<4;kk++)
        kb[cf][kk] = *(const bf16x8*)(kr + cf*4096 + ((64*kk+16*l4) ^ swz));
    }

    f32x4 sacc[2][4] = {{z4,z4,z4,z4},{z4,z4,z4,z4}};
    __builtin_amdgcn_s_setprio(1);
    if (doB){
      #pragma unroll
      for (int cf=0;cf<4;cf++){
        #pragma unroll
        for (int kk=0;kk<4;kk++){
          sacc[0][cf] = __builtin_amdgcn_mfma_f32_16x16x32_bf16(kb[cf][kk], qa[0][kk], sacc[0][cf], 0,0,0);
          sacc[1][cf] = __builtin_amdgcn_mfma_f32_16x16x32_bf16(kb[cf][kk], qa[1][kk], sacc[1][cf], 0,0,0);
        }
      }
    } else {
      #pragma unroll
      for (int cf=0;cf<4;cf++){
        #pragma unroll
        for (int kk=0;kk<4;kk++)
          sacc[0][cf] = __builtin_amdgcn_mfma_f32_16x16x32_bf16(kb[cf][kk], qa[0][kk], sacc[0][cf], 0,0,0);
      }
    }
    __builtin_amdgcn_s_setprio(0);

    // strip A stores
    if (kt < qtA){
      #pragma unroll
      for (int cf=0;cf<4;cf++){
        const int tok0 = k0 + 16*cf + 4*l4;
        f32x4 wv;
        wv[0] = exp2f(sacc[0][cf][0])*si[0];
        wv[1] = exp2f(sacc[0][cf][1])*si[0];
        wv[2] = exp2f(sacc[0][cf][2])*si[0];
        wv[3] = exp2f(sacc[0][cf][3])*si[0];
        *(f32x4*)(wrowA + tok0) = wv;
      }
    } else {
      #pragma unroll
      for (int cf=0;cf<4;cf++){
        const int tok0 = k0 + 16*cf + 4*l4;
        f32x4 wv;
        wv[0] = (tok0+0 <= rA) ? exp2f(sacc[0][cf][0])*si[0] : 0.f;
        wv[1] = (tok0+1 <= rA) ? exp2f(sacc[0][cf][1])*si[0] : 0.f;
        wv[2] = (tok0+2 <= rA) ? exp2f(sacc[0][cf][2])*si[0] : 0.f;
        wv[3] = (tok0+3 <= rA) ? exp2f(sacc[0][cf][3])*si[0] : 0.f;
        *(f32x4*)(wrowA + tok0) = wv;
      }
    }
    // strip B stores
    if (doB){
      if (kt < qtB){
        #pragma unroll
        for (int cf=0;cf<4;cf++){
          const int tok0 = k0 + 16*cf + 4*l4;
          f32x4 wv;
          wv[0] = exp2f(sacc[1][cf][0])*si[1];
          wv[1] = exp2f(sacc[1][cf][1])*si[1];
          wv[2] = exp2f(sacc[1][cf][2])*si[1];
          wv[3] = exp2f(sacc[1][cf][3])*si[1];
          *(f32x4*)(wrowB + tok0) = wv;
        }
      } else {
        #pragma unroll
        for (int cf=0;cf<4;cf++){
          const int tok0 = k0 + 16*cf + 4*l4;
          f32x4 wv;
          wv[0] = (tok0+0 <= rB) ? exp2f(sacc[1][cf][0])*si[1] : 0.f;
          wv[1] = (tok0+1 <= rB) ? exp2f(sacc[1][cf][1])*si[1] : 0.f;
          wv[2] = (tok0+2 <= rB) ? exp2f(sacc[1][cf][2])*si[1] : 0.f;
          wv[3] = (tok0+3 <= rB) ? exp2f(sacc[1][cf][3])*si[1] : 0.f;
          *(f32x4*)(wrowB + tok0) = wv;
        }
      }
    }
  }

  // zero-fill masked region for the wave's 16 A-rows and 16 B-rows
  const f32x4 zz = {0.f,0.f,0.f,0.f};
  {
    const int z0 = nktA*64;
    for (int rr=0; rr<16 && z0 < SQ; rr++){
      float* row = Wbase + (long)(q0A + 16*w + rr)*SQ;
      for (int c = z0 + 4*lane; c < SQ; c += 256)
        *(f32x4*)(row + c) = zz;
    }
  }
  {
    const int z0 = nktB*64;
    for (int rr=0; rr<16; rr++){
      float* row = Wbase + (long)(q0B + 16*w + rr)*SQ;
      for (int c = z0 + 4*lane; c < SQ; c += 256)
        *(f32x4*)(row + c) = zz;
    }
  }
}

extern "C" void kernel_launch(void* const* d_in, const int* in_sizes, int n_in,
                              void* d_out, int out_size, void* d_ws, size_t ws_size,
                              hipStream_t stream) {
  const float* Q = (const float*)d_in[0];
  const float* K = (const float*)d_in[1];
  const float* V = (const float*)d_in[2];
  float* Out = (float*)d_out;
  float* Wout = (float*)d_out + (size_t)BHN*SQ*DD;
  char* dqK  = (char*)d_ws;                                // 16 MB
  char* dqVt = (char*)d_ws + (size_t)BHN*SQ*DD*2;          // 16 MB

  qd_kernel<<<BHN*32, 256, 0, stream>>>(K, V, dqK, dqVt);
  attn_fused<<<512, 256, 0, stream>>>(Q, dqK, dqVt, Out, Wout);
}